// Round 6
// baseline (292.456 us; speedup 1.0000x reference)
//
#include <hip/hip_runtime.h>
#include <float.h>

#define T_TOTAL 32768
#define KC      8192
#define DIM     256

#define LOSS_IDX  ((size_t)T_TOTAL * DIM)      // 8388608
#define USAGE_IDX (LOSS_IDX + 1)

typedef short s16x8 __attribute__((ext_vector_type(8)));
typedef float f32x4 __attribute__((ext_vector_type(4)));

// ws layout (bytes):
#define WS_W2    0                 // u16(bf16)[8192] = 16 KB (was f32)
#define WS_FLAGS 32768             // i32[8192]
#define WS_CBF   65536             // u16[8192*256] = 4 MB

__device__ __forceinline__ unsigned short f2bf(float f) {
    unsigned int u = __float_as_uint(f);
    u += 0x7FFFu + ((u >> 16) & 1u);   // RTNE
    return (unsigned short)(u >> 16);
}

// ---------------------------------------------------------------------------
// prep: cb->bf16 + bf16 w2; flags zero (blocks 0..31); scalars (block 0)
__global__ __launch_bounds__(256) void vq_prep(const float* __restrict__ cb,
                                               unsigned short* __restrict__ cbb,
                                               unsigned short* __restrict__ w2,
                                               int* __restrict__ flags,
                                               float* __restrict__ out) {
    const int blk = blockIdx.x, tid = threadIdx.x;
    size_t i = (size_t)blk * 2048 + (size_t)tid * 8;
    float4 a = *(const float4*)(cb + i);
    float4 b = *(const float4*)(cb + i + 4);
    uint4 o;
    o.x = (unsigned)f2bf(a.x) | ((unsigned)f2bf(a.y) << 16);
    o.y = (unsigned)f2bf(a.z) | ((unsigned)f2bf(a.w) << 16);
    o.z = (unsigned)f2bf(b.x) | ((unsigned)f2bf(b.y) << 16);
    o.w = (unsigned)f2bf(b.z) | ((unsigned)f2bf(b.w) << 16);
    *(uint4*)(cbb + i) = o;
    float s = a.x * a.x + a.y * a.y + a.z * a.z + a.w * a.w
            + b.x * b.x + b.y * b.y + b.z * b.z + b.w * b.w;
    #pragma unroll
    for (int m = 1; m <= 16; m <<= 1) s += __shfl_xor(s, m);
    // bf16 w2: abs err ~5e-9 vs score spread ~1e-3 -> argmin unaffected.
    if ((tid & 31) == 0) w2[blk * 8 + (tid >> 5)] = f2bf(s);
    if (blk < 32) flags[blk * 256 + tid] = 0;
    if (blk == 0 && tid == 0) { out[LOSS_IDX] = 0.0f; out[USAGE_IDX] = 0.0f; }
}

// ---------------------------------------------------------------------------
// main: block = 128 tokens x all 8192 codes, grid 256 (1 block/CU), 8 waves.
// wave w: wr=w>>2 token half (64 tokens, A in 128 regs), wc=w&3 code quarter.
// Private 4-deep wave buffers + rolling vmcnt pipeline (R1 structure, the
// best measured: 171us). R2/R4 sharing experiments falsified the L2-BW
// theory (halving staged bytes made it SLOWER) -> the limit is MLP:
// delivered staging ~ in-flight bytes / latency, and anything that drains
// the FIFO (barriers, or global loads injected by the fold) collapses it.
//
// R5 (two MLP fixes, pipeline byte-identical):
//  1. w2 -> LDS bf16 (prep emits bf16): the fold no longer injects VMEM
//     into the staging FIFO -> no once-per-chunk vmcnt drain.
//  2. Per-wave chunk stagger (off = w*8): waves walk the 64 chunks from
//     different offsets -> breaks the natural 8-wave phase-lock so the
//     MFMA / LDS / staging pipes overlap ACROSS waves (m114 regime; also
//     gives setprio role-diverse waves to arbitrate). Argmin is order-
//     independent given the explicit (s==best && col<bidx) tie-break.
// Pipeline (per wave):
//   iter n: lgkm(0) [prior ds_reads retired -> buf[n&3] recyclable]
//           STAGE(n+4 -> buf[n&3])
//           vmcnt(8) [drains st(n+1); FIFO now holds ONLY staging loads]
//           ds_read frags(n+1) -> regB[(n+1)&1]
//           16 MFMAs on regB[n&1]   (all latencies pre-hidden)
__global__ __launch_bounds__(512, 2) void vq_main(const unsigned short* __restrict__ cbb,
                                                  const unsigned short* __restrict__ w2g,
                                                  const float* __restrict__ z_e,
                                                  const float* __restrict__ cb,
                                                  float* __restrict__ out,
                                                  int* __restrict__ flags) {
    __shared__ unsigned short ca[8][4][2048];   // [wave][buf][4 KB] = 128 KB
    __shared__ unsigned short w2s[KC];          // bf16 w2, 16 KB
    __shared__ unsigned long long smin[128];
    __shared__ float wls[8];

    const int tid  = threadIdx.x;
    const int lane = tid & 63;
    const int w    = tid >> 6;        // 0..7
    const int wr   = w >> 2;          // token half
    const int wc   = w & 3;           // code quarter
    const int quad = lane >> 4;
    const int l15  = lane & 15;
    const int t0   = blockIdx.x * 128;
    const int off  = (w * 8) & 63;    // chunk stagger: de-phase the 8 waves

    if (tid < 128) smin[tid] = ~0ULL;

    // staging: window WIN (0..255 local): chunk gc=((WIN>>2)+off)&63 (codes
    // gc*128+wc*32+row), k-window kw=WIN&3 (k in [kw*64, kw*64+64)). 4 loads
    // x 1 KB, each covering 8 rows x 128 B. Source k-slot XOR-swizzled by
    // row for conflict-free ds_read_b128 later.
    const int srow = lane >> 3;       // 0..7
    const int ssl  = lane & 7;        // LDS slot position
    // full address for (chunk C, kw KW, quarter q):
    //   pstage + C*32768 + KW*64 + q*2048  ==
    //   (C*128 + wc*32 + q*8 + srow)*DIM + KW*64 + (ssl^srow)*8
    const unsigned short* pstage = cbb + (size_t)(wc * 32 + srow) * DIM + (ssl ^ srow) * 8;

    #define STAGE(PC, KW, BP)                                                           \
        {                                                                               \
            _Pragma("unroll")                                                           \
            for (int q = 0; q < 4; ++q) {                                               \
                __builtin_amdgcn_global_load_lds(                                       \
                    (const __attribute__((address_space(1))) void*)((PC) + (KW) * 64 + q * 2048), \
                    (__attribute__((address_space(3))) void*)(&ca[w][BP][q * 512]),     \
                    16, 0, 0);                                                          \
            }                                                                           \
        }

    // 4 hoisted per-lane LDS fragment pointers (kk,j); buffer select BP is a
    // compile-time +BP*2048 elements -> folds into ds_read offset immediate.
    const unsigned short* fragp[4];
    #pragma unroll
    for (int kk = 0; kk < 2; ++kk)
        #pragma unroll
        for (int j = 0; j < 2; ++j) {
            int row = j * 16 + l15;
            int sl = (kk * 4 + quad) ^ (l15 & 7);
            fragp[kk * 2 + j] = &ca[w][0][row * 64 + sl * 8];
        }

    #define READFRAGS(FB, BP)                                                           \
        {                                                                               \
            _Pragma("unroll")                                                           \
            for (int f = 0; f < 4; ++f)                                                 \
                (FB)[f] = *(const s16x8*)(fragp[f] + (BP) * 2048);                      \
        }

    // prologue: w2 -> LDS (16 KB), stage windows 0..3 of chunk 'off',
    // build A from fp32 z_e
    {
        const uint4* s4 = (const uint4*)w2g;   // 1024 x 16 B
        uint4 v0 = s4[tid];
        uint4 v1 = s4[tid + 512];
        ((uint4*)w2s)[tid] = v0;
        ((uint4*)w2s)[tid + 512] = v1;
    }
    const unsigned short* ps0 = pstage + ((size_t)off << 15);
    STAGE(ps0, 0, 0); STAGE(ps0, 1, 1); STAGE(ps0, 2, 2); STAGE(ps0, 3, 3);
    s16x8 af[4][8];
    #pragma unroll
    for (int i = 0; i < 4; ++i) {
        #pragma unroll
        for (int ks = 0; ks < 8; ++ks) {
            const float* p = z_e + (size_t)(t0 + wr * 64 + i * 16 + l15) * DIM + ks * 32 + quad * 8;
            float4 a = *(const float4*)p;
            float4 b = *(const float4*)(p + 4);
            s16x8 v;
            v[0] = (short)f2bf(a.x); v[1] = (short)f2bf(a.y);
            v[2] = (short)f2bf(a.z); v[3] = (short)f2bf(a.w);
            v[4] = (short)f2bf(b.x); v[5] = (short)f2bf(b.y);
            v[6] = (short)f2bf(b.z); v[7] = (short)f2bf(b.w);
            af[i][ks] = v;
        }
    }

    float best[4][4];
    int   bidx[4][4];
    #pragma unroll
    for (int i = 0; i < 4; ++i)
        #pragma unroll
        for (int r = 0; r < 4; ++r) { best[i][r] = FLT_MAX; bidx[i][r] = 0x7FFFFFFF; }

    // prime: drain ALL prologue VMEM (robust to compiler reordering), publish
    // smin + w2s, read window 0. Loop FIFO then holds ONLY staging loads.
    s16x8 regB[2][4];
    __builtin_amdgcn_s_waitcnt(0x0F70);   // vmcnt(0), lgkm/exp unconstrained
    __syncthreads();                       // smin + w2s published
    READFRAGS(regB[0], 0);

    for (int c = 0; c < 64; ++c) {
        const int gc = (c + off) & 63;    // global chunk this iter computes
        f32x4 acc[4][2];
        #pragma unroll
        for (int i = 0; i < 4; ++i)
            #pragma unroll
            for (int j = 0; j < 2; ++j) acc[i][j] = (f32x4){0.f, 0.f, 0.f, 0.f};

        // next-chunk staging base (dummy wrap at c=63 keeps accounting uniform)
        const unsigned short* pcn = pstage + ((size_t)((c + 1 + off) & 63) << 15);

        #pragma unroll
        for (int kw = 0; kw < 4; ++kw) {
            // n = c*4 + kw; n&3 == kw
            // prior ds_reads retired -> buf[kw] is recyclable for staging
            __builtin_amdgcn_s_waitcnt(0xC07F);   // lgkmcnt(0), vmcnt/exp unconstrained
            STAGE(pcn, kw, kw);                   // window n+4 -> buf[n&3]
            // drain staging of window n+1 (leaves newest 8 = st(n+3), st(n+4))
            __builtin_amdgcn_s_waitcnt(0x0F78);   // vmcnt(8), lgkm/exp unconstrained
            READFRAGS(regB[(kw + 1) & 1], (kw + 1) & 3);
            // 16 MFMAs on window n (fragments read one phase ago)
            const s16x8* cur = regB[kw & 1];
            __builtin_amdgcn_s_setprio(1);
            #pragma unroll
            for (int kk = 0; kk < 2; ++kk)
                #pragma unroll
                for (int i = 0; i < 4; ++i)
                    #pragma unroll
                    for (int j = 0; j < 2; ++j)
                        acc[i][j] = __builtin_amdgcn_mfma_f32_16x16x32_bf16(af[i][kw * 2 + kk], cur[kk * 2 + j], acc[i][j], 0, 0, 0);
            __builtin_amdgcn_s_setprio(0);
        }

        // fold chunk gc into running argmin: score = w2[col] - 2*dot.
        // w2 from LDS (bf16) -> zero VMEM in the loop body.
        // Explicit tie-break (col < bidx) keeps lowest index under stagger.
        #pragma unroll
        for (int j = 0; j < 2; ++j) {
            int col = gc * 128 + wc * 32 + j * 16 + l15;
            float w2v = __uint_as_float((unsigned)w2s[col] << 16);
            #pragma unroll
            for (int i = 0; i < 4; ++i)
                #pragma unroll
                for (int r = 0; r < 4; ++r) {
                    float s = fmaf(-2.0f, acc[i][j][r], w2v);
                    if (s < best[i][r] || (s == best[i][r] && col < bidx[i][r])) {
                        best[i][r] = s; bidx[i][r] = col;
                    }
                }
        }
    }

    // cross-lane argmin over the 16 cols held per token row, then merge quarters
    #pragma unroll
    for (int i = 0; i < 4; ++i)
        #pragma unroll
        for (int r = 0; r < 4; ++r) {
            float b = best[i][r]; int ix = bidx[i][r];
            #pragma unroll
            for (int m = 1; m < 16; m <<= 1) {
                float ob = __shfl_xor(b, m);
                int   oi = __shfl_xor(ix, m);
                if (ob < b || (ob == b && oi < ix)) { b = ob; ix = oi; }
            }
            if (l15 == 0) {
                unsigned int fb = __float_as_uint(b);
                fb = (fb & 0x80000000u) ? ~fb : (fb | 0x80000000u);   // monotonic key
                unsigned long long key = ((unsigned long long)fb << 32) | (unsigned int)ix;
                atomicMin(&smin[wr * 64 + i * 16 + quad * 4 + r], key);
            }
        }
    __syncthreads();   // all waves' argmin merged before gather

    // fused gather + loss + flags: wave w -> tokens [w*16, w*16+16)
    float lsum = 0.0f;
    for (int t = w * 16; t < w * 16 + 16; ++t) {
        int tok = t0 + t;
        int k = (int)(unsigned int)(smin[t] & 0xFFFFFFFFull);
        if (lane == 0) flags[k] = 1;   // benign race
        float4 cv = *(const float4*)(cb + (size_t)k * DIM + lane * 4);
        float4 zv = *(const float4*)(z_e + (size_t)tok * DIM + lane * 4);
        float dx = zv.x - cv.x, dy = zv.y - cv.y, dz = zv.z - cv.z, dw = zv.w - cv.w;
        lsum += dx * dx + dy * dy + dz * dz + dw * dw;
        *(float4*)(out + (size_t)tok * DIM + lane * 4) = cv;
    }
    #pragma unroll
    for (int m = 32; m >= 1; m >>= 1) lsum += __shfl_xor(lsum, m);
    if (lane == 0) wls[w] = lsum;
    __syncthreads();
    if (tid == 0) {
        float bsum = 0.0f;
        #pragma unroll
        for (int q = 0; q < 8; ++q) bsum += wls[q];
        // loss = codebook + 0.25*commitment = 1.25 * mean(diff^2)
        atomicAdd(out + LOSS_IDX, bsum * (1.25f / (float)LOSS_IDX));
    }
}

// ---------------------------------------------------------------------------
__global__ __launch_bounds__(256) void vq_usage(const int* __restrict__ flags,
                                                float* __restrict__ out) {
    __shared__ int ws[4];
    int tid = threadIdx.x;
    int s = 0;
    for (int i = tid; i < KC; i += 256) s += flags[i];
    #pragma unroll
    for (int m = 32; m >= 1; m >>= 1) s += __shfl_xor(s, m);
    if ((tid & 63) == 0) ws[tid >> 6] = s;
    __syncthreads();
    if (tid == 0) out[USAGE_IDX] = (float)(ws[0] + ws[1] + ws[2] + ws[3]) / (float)KC;
}

// ---------------------------------------------------------------------------
extern "C" void kernel_launch(void* const* d_in, const int* in_sizes, int n_in,
                              void* d_out, int out_size, void* d_ws, size_t ws_size,
                              hipStream_t stream) {
    (void)in_sizes; (void)n_in; (void)out_size; (void)ws_size;
    const float* z_e = (const float*)d_in[0];
    const float* cb  = (const float*)d_in[1];
    float* out = (float*)d_out;

    char* ws = (char*)d_ws;
    unsigned short* w2  = (unsigned short*)(ws + WS_W2);
    int*   flags = (int*)(ws + WS_FLAGS);
    unsigned short* cbb = (unsigned short*)(ws + WS_CBF);

    vq_prep<<<KC / 8, 256, 0, stream>>>(cb, cbb, w2, flags, out);
    vq_main<<<T_TOTAL / 128, 512, 0, stream>>>(cbb, w2, z_e, cb, out, flags);
    vq_usage<<<1, 256, 0, stream>>>(flags, out);
}

// Round 7
// 260.966 us; speedup vs baseline: 1.1207x; 1.1207x over previous
//
#include <hip/hip_runtime.h>
#include <float.h>

#define T_TOTAL 32768
#define KC      8192
#define DIM     256

#define LOSS_IDX  ((size_t)T_TOTAL * DIM)      // 8388608
#define USAGE_IDX (LOSS_IDX + 1)

typedef short s16x8 __attribute__((ext_vector_type(8)));
typedef float f32x4 __attribute__((ext_vector_type(4)));

// ws layout (bytes):
#define WS_W2    0                 // f32[8192]
#define WS_FLAGS 32768             // i32[8192]
#define WS_CBF   65536             // u16[8192*256] = 4 MB

__device__ __forceinline__ unsigned short f2bf(float f) {
    unsigned int u = __float_as_uint(f);
    u += 0x7FFFu + ((u >> 16) & 1u);   // RTNE
    return (unsigned short)(u >> 16);
}

// ---------------------------------------------------------------------------
// prep: cb->bf16 + exact fp32 w2; flags zero (blocks 0..31); global argmin
// keys (stored in out's z_q slots, 8 B per token) init to ~0 (blocks 0..127);
// scalars (block 0)
__global__ __launch_bounds__(256) void vq_prep(const float* __restrict__ cb,
                                               unsigned short* __restrict__ cbb,
                                               float* __restrict__ w2,
                                               int* __restrict__ flags,
                                               float* __restrict__ out) {
    const int blk = blockIdx.x, tid = threadIdx.x;
    size_t i = (size_t)blk * 2048 + (size_t)tid * 8;
    float4 a = *(const float4*)(cb + i);
    float4 b = *(const float4*)(cb + i + 4);
    uint4 o;
    o.x = (unsigned)f2bf(a.x) | ((unsigned)f2bf(a.y) << 16);
    o.y = (unsigned)f2bf(a.z) | ((unsigned)f2bf(a.w) << 16);
    o.z = (unsigned)f2bf(b.x) | ((unsigned)f2bf(b.y) << 16);
    o.w = (unsigned)f2bf(b.z) | ((unsigned)f2bf(b.w) << 16);
    *(uint4*)(cbb + i) = o;
    float s = a.x * a.x + a.y * a.y + a.z * a.z + a.w * a.w
            + b.x * b.x + b.y * b.y + b.z * b.z + b.w * b.w;
    #pragma unroll
    for (int m = 1; m <= 16; m <<= 1) s += __shfl_xor(s, m);
    if ((tid & 31) == 0) w2[blk * 8 + (tid >> 5)] = s;
    if (blk < 32) flags[blk * 256 + tid] = 0;
    if (blk < 128) {
        int t = blk * 256 + tid;   // 32768 tokens: key slot at out[t*256..+1]
        *(unsigned long long*)(out + ((size_t)t << 8)) = ~0ULL;
    }
    if (blk == 0 && tid == 0) { out[LOSS_IDX] = 0.0f; out[USAGE_IDX] = 0.0f; }
}

// ---------------------------------------------------------------------------
// main: block = 512 tokens x ONE QUARTER of the codebook (2048 codes).
// grid 256 = 64 token-groups x 4 code-quarters; 1 block/CU; 8 waves.
// Wave w handles tokens [t0 + w*64, +64) (A in 128 regs) over ALL 2048 codes.
//
// R6 rationale (L2-BW model, validated by R1/R4/R5): R1's limit was L2->CU
// staging at ~14 B/cyc/CU share: R1 pulled 4 MB/CU (wr-pair L1-dedup'd
// 8 MB demand) -> 300k cyc floor ~ 171us observed. R5's stagger broke the
// L1 dedup -> 8 MB/CU -> 229us (matches 2x floor). Here ALL 8 waves issue
// IDENTICAL staging addresses in natural lockstep (no barriers, private
// 4-deep buffers, R1's exact vmcnt pipeline) -> L1 dedups x8 -> L2 traffic
// 1 MB/CU (75k cyc) -- below the MFMA floor (159k cyc/SIMD = 66us).
// Cross-quarter argmin: global 64-bit atomicMin on monotonic (score,idx)
// keys living in out's z_q slots; vq_gather consumes them afterward.
// Per-wave pipeline (byte-identical to R1):
//   iter n: lgkm(0) [prior ds_reads retired -> buf[n&3] recyclable]
//           STAGE(n+4 -> buf[n&3])
//           vmcnt(8) [drains st(n+1); ample slack]
//           ds_read frags(n+1) -> regB[(n+1)&1]
//           16 MFMAs on regB[n&1]
// Chunk = 32 codes x 256 k (4 k-windows), 64 chunks, 256 iterations.
__global__ __launch_bounds__(512, 2) void vq_main(const unsigned short* __restrict__ cbb,
                                                  const float* __restrict__ w2g,
                                                  const float* __restrict__ z_e,
                                                  float* __restrict__ out) {
    __shared__ unsigned short ca[8][4][2048];   // [wave][buf][4 KB] = 128 KB

    const int tid  = threadIdx.x;
    const int lane = tid & 63;
    const int w    = tid >> 6;        // 0..7 = token octile
    const int quad = lane >> 4;
    const int l15  = lane & 15;
    const int tb   = blockIdx.x >> 2; // token group (512 tokens)
    const int cq   = blockIdx.x & 3;  // code quarter
    const int t0   = tb * 512;
    const int cbase = cq * 2048;

    // staging: chunk c (0..63) = codes cbase + c*32 + row (row 0..31), as 4
    // k-windows kw (k in [kw*64,+64)) of 32 rows x 8 slots x 8 bf16, slot
    // XOR-swizzled by row for conflict-free ds_read_b128. 4 loads x 1 KB per
    // window. ALL 8 waves load the SAME addresses (w-independent) -> L1 dedup.
    const int srow = lane >> 3;       // 0..7
    const int ssl  = lane & 7;        // LDS slot position
    // addr(chunk C, kw KW, octet q) = pstage + C*8192 + q*2048 + KW*64
    //   == (cbase + C*32 + q*8 + srow)*DIM + KW*64 + (ssl^srow)*8
    const unsigned short* pstage = cbb + (size_t)(cbase + srow) * DIM + (ssl ^ srow) * 8;

    #define STAGE(PC, KW, BP)                                                           \
        {                                                                               \
            _Pragma("unroll")                                                           \
            for (int q = 0; q < 4; ++q) {                                               \
                __builtin_amdgcn_global_load_lds(                                       \
                    (const __attribute__((address_space(1))) void*)((PC) + (KW) * 64 + q * 2048), \
                    (__attribute__((address_space(3))) void*)(&ca[w][BP][q * 512]),     \
                    16, 0, 0);                                                          \
            }                                                                           \
        }

    // 4 hoisted per-lane LDS fragment pointers (kk,j); buffer select BP is a
    // compile-time +BP*2048 elements -> folds into ds_read offset immediate.
    const unsigned short* fragp[4];
    #pragma unroll
    for (int kk = 0; kk < 2; ++kk)
        #pragma unroll
        for (int j = 0; j < 2; ++j) {
            int row = j * 16 + l15;
            int sl = (kk * 4 + quad) ^ (l15 & 7);
            fragp[kk * 2 + j] = &ca[w][0][row * 64 + sl * 8];
        }

    #define READFRAGS(FB, BP)                                                           \
        {                                                                               \
            _Pragma("unroll")                                                           \
            for (int f = 0; f < 4; ++f)                                                 \
                (FB)[f] = *(const s16x8*)(fragp[f] + (BP) * 2048);                      \
        }

    // prologue: stage chunk 0's 4 windows, build A from fp32 z_e (64 tokens)
    STAGE(pstage, 0, 0); STAGE(pstage, 1, 1); STAGE(pstage, 2, 2); STAGE(pstage, 3, 3);
    s16x8 af[4][8];
    #pragma unroll
    for (int i = 0; i < 4; ++i) {
        #pragma unroll
        for (int ks = 0; ks < 8; ++ks) {
            const float* p = z_e + (size_t)(t0 + w * 64 + i * 16 + l15) * DIM + ks * 32 + quad * 8;
            float4 a = *(const float4*)p;
            float4 b = *(const float4*)(p + 4);
            s16x8 v;
            v[0] = (short)f2bf(a.x); v[1] = (short)f2bf(a.y);
            v[2] = (short)f2bf(a.z); v[3] = (short)f2bf(a.w);
            v[4] = (short)f2bf(b.x); v[5] = (short)f2bf(b.y);
            v[6] = (short)f2bf(b.z); v[7] = (short)f2bf(b.w);
            af[i][ks] = v;
        }
    }

    float best[4][4];
    int   bidx[4][4];
    #pragma unroll
    for (int i = 0; i < 4; ++i)
        #pragma unroll
        for (int r = 0; r < 4; ++r) { best[i][r] = FLT_MAX; bidx[i][r] = 0x7FFFFFFF; }

    const float* pw2 = w2g + cbase + l15;

    // prime: vmcnt(12) (16 staging + A outstanding; A waited by af uses ->
    // st0 certainly drained). No barrier needed: ca is wave-private.
    s16x8 regB[2][4];
    __builtin_amdgcn_s_waitcnt(0x0F7C);   // vmcnt(12), lgkm/exp unconstrained
    READFRAGS(regB[0], 0);

    for (int c = 0; c < 64; ++c) {
        f32x4 acc[4][2];
        #pragma unroll
        for (int i = 0; i < 4; ++i)
            #pragma unroll
            for (int j = 0; j < 2; ++j) acc[i][j] = (f32x4){0.f, 0.f, 0.f, 0.f};

        // next-chunk staging base (dummy wrap at c=63 keeps accounting uniform)
        const unsigned short* pcn = pstage + ((size_t)((c + 1) & 63) << 13);

        #pragma unroll
        for (int kw = 0; kw < 4; ++kw) {
            // n = c*4 + kw; n&3 == kw
            // prior ds_reads retired -> buf[kw] is recyclable for staging
            __builtin_amdgcn_s_waitcnt(0xC07F);   // lgkmcnt(0), vmcnt/exp unconstrained
            STAGE(pcn, kw, kw);                   // window n+4 -> buf[n&3]
            // drain staging of window n+1 (leaves newest 8 = st(n+3), st(n+4))
            __builtin_amdgcn_s_waitcnt(0x0F78);   // vmcnt(8), lgkm/exp unconstrained
            READFRAGS(regB[(kw + 1) & 1], (kw + 1) & 3);
            // 16 MFMAs on window n (fragments read one phase ago)
            const s16x8* cur = regB[kw & 1];
            __builtin_amdgcn_s_setprio(1);
            #pragma unroll
            for (int kk = 0; kk < 2; ++kk)
                #pragma unroll
                for (int i = 0; i < 4; ++i)
                    #pragma unroll
                    for (int j = 0; j < 2; ++j)
                        acc[i][j] = __builtin_amdgcn_mfma_f32_16x16x32_bf16(af[i][kw * 2 + kk], cur[kk * 2 + j], acc[i][j], 0, 0, 0);
            __builtin_amdgcn_s_setprio(0);
        }

        // fold chunk c into running argmin: score = w2[col] - 2*dot
        #pragma unroll
        for (int j = 0; j < 2; ++j) {
            int col = cbase + c * 32 + j * 16 + l15;
            float w2v = pw2[c * 32 + j * 16];
            #pragma unroll
            for (int i = 0; i < 4; ++i)
                #pragma unroll
                for (int r = 0; r < 4; ++r) {
                    float s = fmaf(-2.0f, acc[i][j][r], w2v);
                    if (s < best[i][r]) { best[i][r] = s; bidx[i][r] = col; }  // ascending col: < keeps lowest
                }
        }
    }

    // cross-lane argmin over the 16 cols held per token row, then global
    // atomicMin merge across the 4 code-quarter blocks (monotonic u64 key)
    #pragma unroll
    for (int i = 0; i < 4; ++i)
        #pragma unroll
        for (int r = 0; r < 4; ++r) {
            float b = best[i][r]; int ix = bidx[i][r];
            #pragma unroll
            for (int m = 1; m < 16; m <<= 1) {
                float ob = __shfl_xor(b, m);
                int   oi = __shfl_xor(ix, m);
                if (ob < b || (ob == b && oi < ix)) { b = ob; ix = oi; }
            }
            if (l15 == 0) {
                unsigned int fb = __float_as_uint(b);
                fb = (fb & 0x80000000u) ? ~fb : (fb | 0x80000000u);   // monotonic key
                unsigned long long key = ((unsigned long long)fb << 32) | (unsigned int)ix;
                int tok = t0 + w * 64 + i * 16 + quad * 4 + r;
                atomicMin((unsigned long long*)(out + ((size_t)tok << 8)), key);
            }
        }
}

// ---------------------------------------------------------------------------
// gather: read final argmin keys from out's z_q slots, gather codebook rows
// (overwriting the keys), fused loss + usage flags. block = 128 tokens.
__global__ __launch_bounds__(256) void vq_gather(const float* __restrict__ cb,
                                                 const float* __restrict__ z_e,
                                                 float* __restrict__ out,
                                                 int* __restrict__ flags) {
    __shared__ float wls[4];
    const int tid  = threadIdx.x;
    const int lane = tid & 63;
    const int w    = tid >> 6;        // 0..3
    const int t0   = blockIdx.x * 128;

    float lsum = 0.0f;
    for (int t = w * 32; t < w * 32 + 32; ++t) {
        int tok = t0 + t;
        // all 64 lanes read the same 8 B key (broadcast load), THEN overwrite
        unsigned long long key = *(const unsigned long long*)(out + ((size_t)tok << 8));
        int k = (int)(unsigned int)(key & 0xFFFFFFFFull);
        if (lane == 0) flags[k] = 1;   // benign race
        float4 cv = *(const float4*)(cb + (size_t)k * DIM + lane * 4);
        float4 zv = *(const float4*)(z_e + (size_t)tok * DIM + lane * 4);
        float dx = zv.x - cv.x, dy = zv.y - cv.y, dz = zv.z - cv.z, dw = zv.w - cv.w;
        lsum += dx * dx + dy * dy + dz * dz + dw * dw;
        *(float4*)(out + ((size_t)tok << 8) + lane * 4) = cv;
    }
    #pragma unroll
    for (int m = 32; m >= 1; m >>= 1) lsum += __shfl_xor(lsum, m);
    if (lane == 0) wls[w] = lsum;
    __syncthreads();
    if (tid == 0) {
        float bsum = wls[0] + wls[1] + wls[2] + wls[3];
        // loss = codebook + 0.25*commitment = 1.25 * mean(diff^2)
        atomicAdd(out + LOSS_IDX, bsum * (1.25f / (float)LOSS_IDX));
    }
}

// ---------------------------------------------------------------------------
__global__ __launch_bounds__(256) void vq_usage(const int* __restrict__ flags,
                                                float* __restrict__ out) {
    __shared__ int ws[4];
    int tid = threadIdx.x;
    int s = 0;
    for (int i = tid; i < KC; i += 256) s += flags[i];
    #pragma unroll
    for (int m = 32; m >= 1; m >>= 1) s += __shfl_xor(s, m);
    if ((tid & 63) == 0) ws[tid >> 6] = s;
    __syncthreads();
    if (tid == 0) out[USAGE_IDX] = (float)(ws[0] + ws[1] + ws[2] + ws[3]) / (float)KC;
}

// ---------------------------------------------------------------------------
extern "C" void kernel_launch(void* const* d_in, const int* in_sizes, int n_in,
                              void* d_out, int out_size, void* d_ws, size_t ws_size,
                              hipStream_t stream) {
    (void)in_sizes; (void)n_in; (void)out_size; (void)ws_size;
    const float* z_e = (const float*)d_in[0];
    const float* cb  = (const float*)d_in[1];
    float* out = (float*)d_out;

    char* ws = (char*)d_ws;
    float* w2    = (float*)(ws + WS_W2);
    int*   flags = (int*)(ws + WS_FLAGS);
    unsigned short* cbb = (unsigned short*)(ws + WS_CBF);

    vq_prep<<<KC / 8, 256, 0, stream>>>(cb, cbb, w2, flags, out);
    vq_main<<<256, 512, 0, stream>>>(cbb, w2, z_e, out);
    vq_gather<<<T_TOTAL / 128, 256, 0, stream>>>(cb, z_e, out, flags);
    vq_usage<<<1, 256, 0, stream>>>(flags, out);
}